// Round 7
// baseline (487.210 us; speedup 1.0000x reference)
//
#include <hip/hip_runtime.h>
#include <hip/hip_cooperative_groups.h>
#include <stdint.h>

#define T_LEN 8192
#define DIN   1024
#define HD    1024
#define TH    3072
#define NB    16      // buckets: 0..14 exact local_step, 15 = clamp (handled by tail_coop)
#define SKINNY_MAX 160  // S <= this -> barrier-free direct-L2 wave-tile path

namespace coop = cooperative_groups;

typedef __attribute__((ext_vector_type(8))) short bf16x8;
typedef __attribute__((ext_vector_type(4))) float f32x4;

__device__ __forceinline__ unsigned short f2bf(float x) {
    union { float f; unsigned u; } v; v.f = x;
    unsigned r = v.u + 0x7FFFu + ((v.u >> 16) & 1u);
    return (unsigned short)(r >> 16);
}

__device__ __forceinline__ float bf2f(unsigned short x) {
    union { unsigned u; float f; } v; v.u = ((unsigned)x) << 16;
    return v.f;
}

// async global->LDS, 16B per lane. LDS dest must be wave-uniform base + lane*16;
// global address may be per-lane arbitrary (gather OK).
__device__ __forceinline__ void gld16(const void* g, void* l) {
    __builtin_amdgcn_global_load_lds(
        (const __attribute__((address_space(1))) unsigned int*)(uintptr_t)g,
        (__attribute__((address_space(3))) unsigned int*)(uintptr_t)l,
        16, 0, 0);
}

__device__ __forceinline__ float sigm(float x) { return 1.f / (1.f + __expf(-x)); }
__device__ __forceinline__ float tanh_fast(float x) { return 1.f - 2.f / (1.f + __expf(2.f * x)); }

// ---------------- cast X -> bf16 (r3 lesson: keep casts OFF the GEMM critical path) ----
__global__ void cast_x(const float* __restrict__ X, unsigned short* __restrict__ Xb) {
    int idx = (blockIdx.x * 256 + threadIdx.x) * 4;
    float4 v = *(const float4*)(X + idx);
    ushort4 o; o.x = f2bf(v.x); o.y = f2bf(v.y); o.z = f2bf(v.z); o.w = f2bf(v.w);
    *(ushort4*)(Xb + idx) = o;
}

// ---------------- transpose+cast Wi/Wh [K][3072] -> [3072][K] bf16 ----------------
__global__ void transpose_cast(const float* __restrict__ Wi, const float* __restrict__ Wh,
                               unsigned short* __restrict__ WiT, unsigned short* __restrict__ WhT) {
    const float* src = blockIdx.z ? Wh : Wi;
    unsigned short* dst = blockIdx.z ? WhT : WiT;
    int n0 = blockIdx.x * 64, k0 = blockIdx.y * 64;
    __shared__ unsigned short tile[64][65];
    int tid = threadIdx.x;
    for (int p = 0; p < 16; p++) {
        int idx = tid + p * 256;
        int kl = idx >> 6, nl = idx & 63;
        tile[kl][nl] = f2bf(src[(size_t)(k0 + kl) * TH + n0 + nl]);
    }
    __syncthreads();
    for (int p = 0; p < 16; p++) {
        int idx = tid + p * 256;
        int nl = idx >> 6, kl = idx & 63;
        dst[(size_t)(n0 + nl) * 1024 + k0 + kl] = tile[kl][nl];
    }
}

// ---------------- segment metadata (1 block, 1024 threads) ----------------
// meta[0..NB): counts ; meta[NB..2NB): offsets ; meta[2NB]: last_state nonzero flag
__global__ void meta_kernel(const int* __restrict__ term, const float* __restrict__ last_state,
                            int* __restrict__ pos_list, int* __restrict__ meta) {
    __shared__ int part[1024];
    __shared__ int cnt[NB];
    __shared__ int cur[NB];
    __shared__ int flag;
    int tid = threadIdx.x;
    if (tid < NB) cnt[tid] = 0;
    if (tid == 0) flag = 0;
    __syncthreads();
    int base = tid * 8;
    int mx = -1;
    for (int u = 0; u < 8; u++) {
        int t = base + u;
        int s = (t == 0 || term[t] != 0) ? t : -1;
        mx = s > mx ? s : mx;
    }
    part[tid] = mx;
    __syncthreads();
    for (int d = 1; d < 1024; d <<= 1) {
        int a = part[tid];
        int b = (tid >= d) ? part[tid - d] : -1;
        __syncthreads();
        part[tid] = a > b ? a : b;
        __syncthreads();
    }
    int run = (tid > 0) ? part[tid - 1] : -1;
    int kk[8];
    for (int u = 0; u < 8; u++) {
        int t = base + u;
        int s = (t == 0 || term[t] != 0) ? t : -1;
        run = s > run ? s : run;
        int ls = t - run;
        int k = ls < NB ? ls : NB - 1;
        kk[u] = k;
        atomicAdd(&cnt[k], 1);
    }
    if (last_state[tid] != 0.0f) atomicOr(&flag, 1);
    __syncthreads();
    if (tid == 0) {
        int off = 0;
        for (int k = 0; k < NB; k++) {
            meta[k] = cnt[k];
            meta[NB + k] = off;
            cur[k] = off;
            off += cnt[k];
        }
        meta[2 * NB] = flag;
    }
    __syncthreads();
    for (int u = 0; u < 8; u++) {
        int idx = atomicAdd(&cur[kk[u]], 1);
        pos_list[idx] = base + u;
    }
}

// ---------------- gi = Xb @ WiT^T + bi  (BK=64, m97-style barrier amortization) -------
// r2 post-mortem: BK=32 form ran 665 TF with 2 barriers per 16 MFMAs; m97 ladder says
// the 128^2/BK=64 form (2 barriers per 32 MFMAs, 16B gld16 staging) reaches 874-912 TF.
// Fragment math and epilogue unchanged; only K-blocking doubled.
__global__ __launch_bounds__(256) void gemm_gi(const unsigned short* __restrict__ Xb,
                                               const unsigned short* __restrict__ WiT,
                                               const float* __restrict__ bi,
                                               float* __restrict__ gi) {
    __shared__ unsigned short As[128 * 64];   // 16 KB
    __shared__ unsigned short Bs[128 * 64];   // 16 KB
    int tid = threadIdx.x;
    int m0 = blockIdx.y * 128, n0 = blockIdx.x * 128;
    int lane = tid & 63, wave = tid >> 6;
    int wm = wave & 1, wn = wave >> 1;
    int quad = lane >> 4, l16 = lane & 15;
    f32x4 acc[4][4] = {};   // 16 f32x4 = promotion ceiling; do NOT enlarge (r2: 24 -> scratch spill)
    for (int kb = 0; kb < 16; kb++) {
        int k0 = kb * 64;
        for (int p = 0; p < 4; p++) {
            int c = tid + p * 256;            // 1024 chunks of 16B per matrix
            int row = c >> 3, cb = c & 7;
            gld16(Xb + (size_t)(m0 + row) * 1024 + k0 + cb * 8, As + c * 8);
            gld16(WiT + (size_t)(n0 + row) * 1024 + k0 + cb * 8, Bs + c * 8);
        }
        __syncthreads();
        for (int ks = 0; ks < 2; ks++) {
            bf16x8 af[4], bfr[4];
            for (int i = 0; i < 4; i++)
                af[i] = *(const bf16x8*)(As + (wm * 64 + i * 16 + l16) * 64 + ks * 32 + quad * 8);
            for (int j = 0; j < 4; j++)
                bfr[j] = *(const bf16x8*)(Bs + (wn * 64 + j * 16 + l16) * 64 + ks * 32 + quad * 8);
            for (int i = 0; i < 4; i++)
                for (int j = 0; j < 4; j++)
                    acc[i][j] = __builtin_amdgcn_mfma_f32_16x16x32_bf16(af[i], bfr[j], acc[i][j], 0, 0, 0);
        }
        __syncthreads();
    }
    for (int j = 0; j < 4; j++) {
        int col = n0 + wn * 64 + j * 16 + l16;
        float bv = bi[col];
        for (int i = 0; i < 4; i++) {
            int rbase = m0 + wm * 64 + i * 16 + quad * 4;
            for (int r = 0; r < 4; r++)
                gi[(size_t)(rbase + r) * TH + col] = acc[i][j][r] + bv;
        }
    }
}

// ---------------- pass 0: segment starts, h_prev == 0 (or last_state for t==0) ----------
__global__ void pass0_kernel(const float* __restrict__ gi, const float* __restrict__ bhn,
                             const float* __restrict__ last_state, const float* __restrict__ Wh,
                             const int* __restrict__ term, const int* __restrict__ pos_list,
                             const int* __restrict__ meta, float* __restrict__ out,
                             unsigned short* __restrict__ hb) {
    int S0 = meta[0];
    int b = blockIdx.x;
    if (b >= S0) return;
    int t = pos_list[meta[NB] + b];
    int tid = threadIdx.x;
    bool ls_path = (t == 0) && (term[0] == 0) && (meta[2 * NB] != 0);
    for (int u = 0; u < 4; u++) {
        int j = tid + u * 256;
        float gr = gi[(size_t)t * TH + j];
        float gz = gi[(size_t)t * TH + 1024 + j];
        float gn = gi[(size_t)t * TH + 2048 + j];
        float hp = 0.f, ghr = 0.f, ghz = 0.f, ghn = 0.f;
        if (ls_path) {  // general fallback (last_state != 0); not taken for this dataset
            hp = last_state[j];
            for (int k = 0; k < 1024; k++) {
                float hk = last_state[k];
                const float* w = Wh + (size_t)k * TH;
                ghr += hk * w[j]; ghz += hk * w[1024 + j]; ghn += hk * w[2048 + j];
            }
        }
        float r = sigm(gr + ghr);
        float z = sigm(gz + ghz);
        float n = tanh_fast(gn + r * (ghn + bhn[j]));
        float h = (1.f - z) * n + z * hp;
        out[(size_t)t * HD + j] = h;
        out[(size_t)(T_LEN + t) * HD + j] = h;
        hb[(size_t)t * HD + j] = f2bf(h);
    }
}

// ---------------- pass k in [1,14]: gathered-row GEMM h_prev @ Wh + fused gates --------
// Two paths selected at runtime on S = meta[k] (uniform across grid):
//  - S >  SKINNY_MAX: LDS path (verified round-0 form).
//  - S <= SKINNY_MAX: skinny barrier-free direct-L2 wave-tile path (verified round-2).
__global__ __launch_bounds__(256) void pass_gemm(const float* __restrict__ gi,
                                                 const float* __restrict__ bhn,
                                                 const unsigned short* __restrict__ WhT,
                                                 const unsigned short* __restrict__ hb,
                                                 float* __restrict__ out,
                                                 unsigned short* __restrict__ hbw,
                                                 const int* __restrict__ pos_list,
                                                 const int* __restrict__ meta, int k) {
    int S = meta[k];
    int off = meta[NB + k];
    int tid = threadIdx.x;
    int lane = tid & 63, wave = tid >> 6;
    int quad = lane >> 4, l16 = lane & 15;

    if (S <= SKINNY_MAX) {
        if (S == 0) return;
        int nrt = (S + 15) >> 4;
        int ntask = 64 * nrt;                       // 64 h-col tiles x row tiles
        int gwave = ((blockIdx.y * 16 + blockIdx.x) << 2) + wave;
        int nw = gridDim.x * gridDim.y * 4;
        for (int task = gwave; task < ntask; task += nw) {
            int ct = task & 63;
            int rt = task >> 6;
            int j = ct * 16 + l16;                  // h-col this lane owns
            int ra = rt * 16 + l16;
            ra = ra < S ? ra : S - 1;               // clamp: dup loads harmless
            int t_a = pos_list[off + ra];
            const unsigned short* ap = hb + (size_t)(t_a - 1) * HD + quad * 8;
            const unsigned short* bp = WhT + (size_t)j * 1024 + quad * 8;
            f32x4 acc[3] = {};
            #pragma unroll
            for (int ks = 0; ks < 32; ks++) {
                bf16x8 a  = *(const bf16x8*)(ap + ks * 32);
                bf16x8 b0 = *(const bf16x8*)(bp + ks * 32);
                bf16x8 b1 = *(const bf16x8*)(bp + 1048576 + ks * 32);   // gate z row block
                bf16x8 b2 = *(const bf16x8*)(bp + 2097152 + ks * 32);   // gate n row block
                acc[0] = __builtin_amdgcn_mfma_f32_16x16x32_bf16(a, b0, acc[0], 0, 0, 0);
                acc[1] = __builtin_amdgcn_mfma_f32_16x16x32_bf16(a, b1, acc[1], 0, 0, 0);
                acc[2] = __builtin_amdgcn_mfma_f32_16x16x32_bf16(a, b2, acc[2], 0, 0, 0);
            }
            // C layout: col = l16 (h-col j), row = quad*4 + r (row within 16-row tile)
            #pragma unroll
            for (int r = 0; r < 4; r++) {
                int rr = rt * 16 + quad * 4 + r;
                if (rr >= S) continue;
                int t = pos_list[off + rr];
                const float* girow = gi + (size_t)t * TH;
                float hp = out[(size_t)(t - 1) * HD + j];
                float rgt = sigm(girow[j] + acc[0][r]);
                float zgt = sigm(girow[1024 + j] + acc[1][r]);
                float ngt = tanh_fast(girow[2048 + j] + rgt * (acc[2][r] + bhn[j]));
                float hv = (1.f - zgt) * ngt + zgt * hp;
                out[(size_t)t * HD + j] = hv;
                out[(size_t)(T_LEN + t) * HD + j] = hv;
                hbw[(size_t)t * HD + j] = f2bf(hv);
            }
        }
        return;
    }

    // ---------------- LDS path (verified round-0 form) ----------------
    int r0 = blockIdx.y * 64;
    if (r0 >= S) return;
    int j0 = blockIdx.x * 64;
    __shared__ unsigned short As[4 * 64 * 32];    // 16 KB (four 32-K sub-tiles)
    __shared__ unsigned short Bs[4 * 192 * 32];   // 48 KB (row: gate g*64 + jj)
    int wm = wave & 1, wn = wave >> 1;

    // A gather: 256 chunks per sub-tile; chunk id = tid; row=tid>>2, sub=tid&3.
    int arow = tid >> 2, sub = tid & 3;
    bool av = (r0 + arow) < S;
    int t_a = av ? pos_list[off + r0 + arow] : 1;
    const unsigned short* hsrc = hb + (size_t)(t_a - 1) * HD + sub * 8;

    f32x4 acc[2][6] = {};
    for (int kb = 0; kb < 8; kb++) {
        int k0 = kb * 128;
        for (int ks = 0; ks < 4; ks++) {
            int kk0 = k0 + ks * 32;
            for (int p = 0; p < 3; p++) {      // B sub-tile: 768 chunks
                int c = tid + p * 256;
                int row = c >> 2, q = c & 3;
                int g = row >> 6, jj = row & 63;
                gld16(WhT + (size_t)(g * 1024 + j0 + jj) * 1024 + kk0 + q * 8,
                      Bs + ks * 6144 + c * 8);
            }
            // A sub-tile: 256 chunks (gathered rows; garbage rows >= S harmless)
            gld16(hsrc + kk0, As + ks * 2048 + tid * 8);
        }
        __syncthreads();
        for (int ks = 0; ks < 4; ks++) {
            bf16x8 af[2];
            for (int i = 0; i < 2; i++)
                af[i] = *(const bf16x8*)(As + ks * 2048 + (wm * 32 + i * 16 + l16) * 32 + quad * 8);
            for (int n = 0; n < 6; n++) {
                int g = n >> 1, jh = n & 1;
                bf16x8 bv = *(const bf16x8*)(Bs + ks * 6144 + (g * 64 + wn * 32 + jh * 16 + l16) * 32 + quad * 8);
                for (int i = 0; i < 2; i++)
                    acc[i][n] = __builtin_amdgcn_mfma_f32_16x16x32_bf16(af[i], bv, acc[i][n], 0, 0, 0);
            }
        }
        __syncthreads();
    }
    // epilogue: rows r0 + wm*32 + i*16 + quad*4 + r ; cols j0 + wn*32 + jh*16 + l16
    for (int i = 0; i < 2; i++) {
        for (int r = 0; r < 4; r++) {
            int rr = r0 + wm * 32 + i * 16 + quad * 4 + r;
            if (rr >= S) continue;
            int t = pos_list[off + rr];
            const float* girow = gi + (size_t)t * TH;
            const float* hprow = out + (size_t)(t - 1) * HD;
            float* o1 = out + (size_t)t * HD;
            float* o2 = out + (size_t)(T_LEN + t) * HD;
            unsigned short* hbrow = hbw + (size_t)t * HD;
            for (int jh = 0; jh < 2; jh++) {
                int j = j0 + wn * 32 + jh * 16 + l16;
                float ghr = acc[i][0 + jh][r];
                float ghz = acc[i][2 + jh][r];
                float ghn = acc[i][4 + jh][r];
                float rg = sigm(girow[j] + ghr);
                float zg = sigm(girow[1024 + j] + ghz);
                float ng = tanh_fast(girow[2048 + j] + rg * (ghn + bhn[j]));
                float h = (1.f - zg) * ng + zg * hprow[j];
                o1[j] = h;
                o2[j] = h;
                hbrow[j] = f2bf(h);
            }
        }
    }
}

// ---------------- tail: positions with local_step >= NB-1, sequential per time order ----
// r2 post-mortem: the old single-block tail read the FULL 12 MB f32 Wh per step on ONE
// CU (~89 us/step) — the likely source of the ~90-180 us unexplained budget (and the
// ~80 us residual in round 1's budget). Now a 16-block cooperative kernel: each block
// owns 64 h-cols (192 bf16 WhT dot-rows, 384 KB/block/step), h_prev staged in LDS,
// device-fence + grid.sync between the (few) sequential steps. If S==0, exits early.
__global__ __launch_bounds__(256) void tail_coop(const float* __restrict__ gi,
                                                 const float* __restrict__ bhn,
                                                 const unsigned short* __restrict__ WhT,
                                                 const int* __restrict__ pos_list,
                                                 const int* __restrict__ meta,
                                                 float* __restrict__ out) {
    int S = meta[NB - 1];
    if (S == 0) return;
    __shared__ int pos[T_LEN];        // 32 KB: correctness path for any S
    __shared__ float hsh[HD];
    __shared__ float dots[192];
    int off = meta[NB + NB - 1];
    int tid = threadIdx.x;
    int j0 = blockIdx.x * 64;
    for (int i = tid; i < S; i += 256) pos[i] = pos_list[off + i];
    __syncthreads();
    if (tid == 0) {   // insertion sort by t (S expected tiny; redundant per block)
        for (int i = 1; i < S; i++) {
            int v = pos[i], j = i - 1;
            while (j >= 0 && pos[j] > v) { pos[j + 1] = pos[j]; j--; }
            pos[j + 1] = v;
        }
    }
    __syncthreads();
    coop::grid_group grid = coop::this_grid();
    for (int s = 0; s < S; s++) {
        int t = pos[s];
        for (int u = 0; u < 4; u++)    // stage h_prev (f32, from out)
            hsh[tid + u * 256] = out[(size_t)(t - 1) * HD + tid + u * 256];
        __syncthreads();
        if (tid < 192) {
            int g = tid >> 6, jj = tid & 63;
            int col = g * 1024 + j0 + jj;
            const unsigned short* wrow = WhT + (size_t)col * 1024;
            float acc = 0.f;
            for (int kk = 0; kk < 1024; kk += 8) {
                bf16x8 wv = *(const bf16x8*)(wrow + kk);
                f32x4 h0 = *(const f32x4*)(hsh + kk);
                f32x4 h1 = *(const f32x4*)(hsh + kk + 4);
                acc += h0[0] * bf2f((unsigned short)wv[0]) + h0[1] * bf2f((unsigned short)wv[1])
                     + h0[2] * bf2f((unsigned short)wv[2]) + h0[3] * bf2f((unsigned short)wv[3])
                     + h1[0] * bf2f((unsigned short)wv[4]) + h1[1] * bf2f((unsigned short)wv[5])
                     + h1[2] * bf2f((unsigned short)wv[6]) + h1[3] * bf2f((unsigned short)wv[7]);
            }
            dots[tid] = acc;
        }
        __syncthreads();
        if (tid < 64) {
            int j = j0 + tid;
            float rg = sigm(gi[(size_t)t * TH + j] + dots[tid]);
            float zg = sigm(gi[(size_t)t * TH + 1024 + j] + dots[64 + tid]);
            float ng = tanh_fast(gi[(size_t)t * TH + 2048 + j] + rg * (dots[128 + tid] + bhn[j]));
            float hv = (1.f - zg) * ng + zg * hsh[j];
            out[(size_t)t * HD + j] = hv;
            out[(size_t)(T_LEN + t) * HD + j] = hv;
        }
        __threadfence();
        grid.sync();
    }
}

extern "C" void kernel_launch(void* const* d_in, const int* in_sizes, int n_in,
                              void* d_out, int out_size, void* d_ws, size_t ws_size,
                              hipStream_t stream) {
    const float* X          = (const float*)d_in[0];
    const int*   term       = (const int*)d_in[1];
    const float* last_state = (const float*)d_in[2];
    const float* Wi         = (const float*)d_in[3];
    const float* bi         = (const float*)d_in[4];
    const float* Wh         = (const float*)d_in[5];
    const float* bhn        = (const float*)d_in[6];
    float* out = (float*)d_out;

    char* ws = (char*)d_ws;
    float*          gi       = (float*)ws;                         // 100,663,296 B
    unsigned short* Xb       = (unsigned short*)(ws + 100663296);  // 16,777,216 B (reused as hb)
    unsigned short* hb       = Xb;  // Xb dead after gemm_gi; stream order guarantees safety
    unsigned short* WiT      = (unsigned short*)(ws + 117440512);  //  6,291,456 B
    unsigned short* WhT      = (unsigned short*)(ws + 123731968);  //  6,291,456 B
    int*            pos_list = (int*)(ws + 130023424);             //     32,768 B
    int*            meta     = (int*)(ws + 130056192);             //        512 B

    cast_x<<<dim3(8192), dim3(256), 0, stream>>>(X, Xb);
    transpose_cast<<<dim3(48, 16, 2), dim3(256), 0, stream>>>(Wi, Wh, WiT, WhT);
    meta_kernel<<<dim3(1), dim3(1024), 0, stream>>>(term, last_state, pos_list, meta);
    gemm_gi<<<dim3(24, 64), dim3(256), 0, stream>>>(Xb, WiT, bi, gi);
    pass0_kernel<<<dim3(8192), dim3(256), 0, stream>>>(gi, bhn, last_state, Wh, term, pos_list, meta, out, hb);
    for (int k = 1; k < NB - 1; k++) {
        int rows_max = T_LEN / (k + 1);     // S_k <= T/(k+1)
        int gy = (rows_max + 63) / 64;
        pass_gemm<<<dim3(16, gy), dim3(256), 0, stream>>>(gi, bhn, WhT, hb, out, hb, pos_list, meta, k);
    }
    {   // parallel tail (cooperative: sequential steps with device-scope sync)
        void* args[] = { (void*)&gi, (void*)&bhn, (void*)&WhT,
                         (void*)&pos_list, (void*)&meta, (void*)&out };
        hipLaunchCooperativeKernel((void*)tail_coop, dim3(16), dim3(256),
                                   args, 0, stream);
    }
}

// Round 9
// 430.766 us; speedup vs baseline: 1.1310x; 1.1310x over previous
//
#include <hip/hip_runtime.h>
#include <stdint.h>

#define T_LEN 8192
#define DIN   1024
#define HD    1024
#define TH    3072
#define NB    16      // buckets: 0..14 exact local_step, 15 = clamp (handled by tail_pll)
#define SKINNY_MAX 160  // S <= this -> barrier-free direct-L2 wave-tile path

typedef __attribute__((ext_vector_type(8))) short bf16x8;
typedef __attribute__((ext_vector_type(4))) float f32x4;

__device__ __forceinline__ unsigned short f2bf(float x) {
    union { float f; unsigned u; } v; v.f = x;
    unsigned r = v.u + 0x7FFFu + ((v.u >> 16) & 1u);
    return (unsigned short)(r >> 16);
}

__device__ __forceinline__ float bf2f(unsigned short x) {
    union { unsigned u; float f; } v; v.u = ((unsigned)x) << 16;
    return v.f;
}

// async global->LDS, 16B per lane. LDS dest must be wave-uniform base + lane*16;
// global address may be per-lane arbitrary (gather OK).
__device__ __forceinline__ void gld16(const void* g, void* l) {
    __builtin_amdgcn_global_load_lds(
        (const __attribute__((address_space(1))) unsigned int*)(uintptr_t)g,
        (__attribute__((address_space(3))) unsigned int*)(uintptr_t)l,
        16, 0, 0);
}

__device__ __forceinline__ float sigm(float x) { return 1.f / (1.f + __expf(-x)); }
__device__ __forceinline__ float tanh_fast(float x) { return 1.f - 2.f / (1.f + __expf(2.f * x)); }

// ---------------- cast X -> bf16 ----------------
__global__ void cast_x(const float* __restrict__ X, unsigned short* __restrict__ Xb) {
    int idx = (blockIdx.x * 256 + threadIdx.x) * 4;
    float4 v = *(const float4*)(X + idx);
    ushort4 o; o.x = f2bf(v.x); o.y = f2bf(v.y); o.z = f2bf(v.z); o.w = f2bf(v.w);
    *(ushort4*)(Xb + idx) = o;
}

// ---------------- transpose+cast Wi/Wh [K][3072] -> [3072][K] bf16 ----------------
__global__ void transpose_cast(const float* __restrict__ Wi, const float* __restrict__ Wh,
                               unsigned short* __restrict__ WiT, unsigned short* __restrict__ WhT) {
    const float* src = blockIdx.z ? Wh : Wi;
    unsigned short* dst = blockIdx.z ? WhT : WiT;
    int n0 = blockIdx.x * 64, k0 = blockIdx.y * 64;
    __shared__ unsigned short tile[64][65];
    int tid = threadIdx.x;
    for (int p = 0; p < 16; p++) {
        int idx = tid + p * 256;
        int kl = idx >> 6, nl = idx & 63;
        tile[kl][nl] = f2bf(src[(size_t)(k0 + kl) * TH + n0 + nl]);
    }
    __syncthreads();
    for (int p = 0; p < 16; p++) {
        int idx = tid + p * 256;
        int nl = idx >> 6, kl = idx & 63;
        dst[(size_t)(n0 + nl) * 1024 + k0 + kl] = tile[kl][nl];
    }
}

// ---------------- segment metadata (1 block, 1024 threads) ----------------
// meta[0..NB): counts ; meta[NB..2NB): offsets ; meta[2NB]: last_state flag ;
// meta[48]: inter-block sync counter for tail_pll (zeroed here every call)
__global__ void meta_kernel(const int* __restrict__ term, const float* __restrict__ last_state,
                            int* __restrict__ pos_list, int* __restrict__ meta) {
    __shared__ int part[1024];
    __shared__ int cnt[NB];
    __shared__ int cur[NB];
    __shared__ int flag;
    int tid = threadIdx.x;
    if (tid < NB) cnt[tid] = 0;
    if (tid == 0) flag = 0;
    __syncthreads();
    int base = tid * 8;
    int mx = -1;
    for (int u = 0; u < 8; u++) {
        int t = base + u;
        int s = (t == 0 || term[t] != 0) ? t : -1;
        mx = s > mx ? s : mx;
    }
    part[tid] = mx;
    __syncthreads();
    for (int d = 1; d < 1024; d <<= 1) {
        int a = part[tid];
        int b = (tid >= d) ? part[tid - d] : -1;
        __syncthreads();
        part[tid] = a > b ? a : b;
        __syncthreads();
    }
    int run = (tid > 0) ? part[tid - 1] : -1;
    int kk[8];
    for (int u = 0; u < 8; u++) {
        int t = base + u;
        int s = (t == 0 || term[t] != 0) ? t : -1;
        run = s > run ? s : run;
        int ls = t - run;
        int k = ls < NB ? ls : NB - 1;
        kk[u] = k;
        atomicAdd(&cnt[k], 1);
    }
    if (last_state[tid] != 0.0f) atomicOr(&flag, 1);
    __syncthreads();
    if (tid == 0) {
        int off = 0;
        for (int k = 0; k < NB; k++) {
            meta[k] = cnt[k];
            meta[NB + k] = off;
            cur[k] = off;
            off += cnt[k];
        }
        meta[2 * NB] = flag;
        meta[48] = 0;                 // tail_pll barrier counter
    }
    __syncthreads();
    for (int u = 0; u < 8; u++) {
        int idx = atomicAdd(&cur[kk[u]], 1);
        pos_list[idx] = base + u;
    }
}

// ---------------- gi = Xb @ WiT^T + bi  (REVERTED to verified BK=32 form: 77.5 us) ----
// r7 post-mortem: BK=64 regressed to 89.7 us — LDS row stride 128B tripled bank
// conflicts (6.3M -> 18.9M) and 32KB LDS cut occupancy 28 -> 19%. BK=32 (64B stride)
// is the measured optimum for this structure. Do NOT raise BK again.
__global__ __launch_bounds__(256) void gemm_gi(const unsigned short* __restrict__ Xb,
                                               const unsigned short* __restrict__ WiT,
                                               const float* __restrict__ bi,
                                               float* __restrict__ gi) {
    __shared__ unsigned short As[128 * 32];
    __shared__ unsigned short Bs[128 * 32];
    int tid = threadIdx.x;
    int m0 = blockIdx.y * 128, n0 = blockIdx.x * 128;
    int lane = tid & 63, wave = tid >> 6;
    int wm = wave & 1, wn = wave >> 1;
    int quad = lane >> 4, l16 = lane & 15;
    f32x4 acc[4][4] = {};   // 16 f32x4 = promotion ceiling; do NOT enlarge (r2: 24 -> scratch spill)
    for (int kb = 0; kb < 32; kb++) {
        int k0 = kb * 32;
        for (int p = 0; p < 2; p++) {
            int c = tid + p * 256;
            int row = c >> 2, cb = c & 3;
            gld16(Xb + (size_t)(m0 + row) * 1024 + k0 + cb * 8, As + c * 8);
            gld16(WiT + (size_t)(n0 + row) * 1024 + k0 + cb * 8, Bs + c * 8);
        }
        __syncthreads();
        bf16x8 af[4], bfr[4];
        for (int i = 0; i < 4; i++)
            af[i] = *(const bf16x8*)(As + (wm * 64 + i * 16 + l16) * 32 + quad * 8);
        for (int j = 0; j < 4; j++)
            bfr[j] = *(const bf16x8*)(Bs + (wn * 64 + j * 16 + l16) * 32 + quad * 8);
        for (int i = 0; i < 4; i++)
            for (int j = 0; j < 4; j++)
                acc[i][j] = __builtin_amdgcn_mfma_f32_16x16x32_bf16(af[i], bfr[j], acc[i][j], 0, 0, 0);
        __syncthreads();
    }
    for (int j = 0; j < 4; j++) {
        int col = n0 + wn * 64 + j * 16 + l16;
        float bv = bi[col];
        for (int i = 0; i < 4; i++) {
            int rbase = m0 + wm * 64 + i * 16 + quad * 4;
            for (int r = 0; r < 4; r++)
                gi[(size_t)(rbase + r) * TH + col] = acc[i][j][r] + bv;
        }
    }
}

// ---------------- pass 0: segment starts, h_prev == 0 (or last_state for t==0) ----------
__global__ void pass0_kernel(const float* __restrict__ gi, const float* __restrict__ bhn,
                             const float* __restrict__ last_state, const float* __restrict__ Wh,
                             const int* __restrict__ term, const int* __restrict__ pos_list,
                             const int* __restrict__ meta, float* __restrict__ out,
                             unsigned short* __restrict__ hb) {
    int S0 = meta[0];
    int b = blockIdx.x;
    if (b >= S0) return;
    int t = pos_list[meta[NB] + b];
    int tid = threadIdx.x;
    bool ls_path = (t == 0) && (term[0] == 0) && (meta[2 * NB] != 0);
    for (int u = 0; u < 4; u++) {
        int j = tid + u * 256;
        float gr = gi[(size_t)t * TH + j];
        float gz = gi[(size_t)t * TH + 1024 + j];
        float gn = gi[(size_t)t * TH + 2048 + j];
        float hp = 0.f, ghr = 0.f, ghz = 0.f, ghn = 0.f;
        if (ls_path) {  // general fallback (last_state != 0); not taken for this dataset
            hp = last_state[j];
            for (int k = 0; k < 1024; k++) {
                float hk = last_state[k];
                const float* w = Wh + (size_t)k * TH;
                ghr += hk * w[j]; ghz += hk * w[1024 + j]; ghn += hk * w[2048 + j];
            }
        }
        float r = sigm(gr + ghr);
        float z = sigm(gz + ghz);
        float n = tanh_fast(gn + r * (ghn + bhn[j]));
        float h = (1.f - z) * n + z * hp;
        out[(size_t)t * HD + j] = h;
        out[(size_t)(T_LEN + t) * HD + j] = h;
        hb[(size_t)t * HD + j] = f2bf(h);
    }
}

// ---------------- pass k in [1,14]: gathered-row GEMM h_prev @ Wh + fused gates --------
// Two paths selected at runtime on S = meta[k] (uniform across grid):
//  - S >  SKINNY_MAX: LDS path (verified round-0 form).
//  - S <= SKINNY_MAX: skinny barrier-free direct-L2 wave-tile path (verified round-2).
__global__ __launch_bounds__(256) void pass_gemm(const float* __restrict__ gi,
                                                 const float* __restrict__ bhn,
                                                 const unsigned short* __restrict__ WhT,
                                                 const unsigned short* __restrict__ hb,
                                                 float* __restrict__ out,
                                                 unsigned short* __restrict__ hbw,
                                                 const int* __restrict__ pos_list,
                                                 const int* __restrict__ meta, int k) {
    int S = meta[k];
    int off = meta[NB + k];
    int tid = threadIdx.x;
    int lane = tid & 63, wave = tid >> 6;
    int quad = lane >> 4, l16 = lane & 15;

    if (S <= SKINNY_MAX) {
        if (S == 0) return;
        int nrt = (S + 15) >> 4;
        int ntask = 64 * nrt;                       // 64 h-col tiles x row tiles
        int gwave = ((blockIdx.y * 16 + blockIdx.x) << 2) + wave;
        int nw = gridDim.x * gridDim.y * 4;
        for (int task = gwave; task < ntask; task += nw) {
            int ct = task & 63;
            int rt = task >> 6;
            int j = ct * 16 + l16;                  // h-col this lane owns
            int ra = rt * 16 + l16;
            ra = ra < S ? ra : S - 1;               // clamp: dup loads harmless
            int t_a = pos_list[off + ra];
            const unsigned short* ap = hb + (size_t)(t_a - 1) * HD + quad * 8;
            const unsigned short* bp = WhT + (size_t)j * 1024 + quad * 8;
            f32x4 acc[3] = {};
            #pragma unroll
            for (int ks = 0; ks < 32; ks++) {
                bf16x8 a  = *(const bf16x8*)(ap + ks * 32);
                bf16x8 b0 = *(const bf16x8*)(bp + ks * 32);
                bf16x8 b1 = *(const bf16x8*)(bp + 1048576 + ks * 32);   // gate z row block
                bf16x8 b2 = *(const bf16x8*)(bp + 2097152 + ks * 32);   // gate n row block
                acc[0] = __builtin_amdgcn_mfma_f32_16x16x32_bf16(a, b0, acc[0], 0, 0, 0);
                acc[1] = __builtin_amdgcn_mfma_f32_16x16x32_bf16(a, b1, acc[1], 0, 0, 0);
                acc[2] = __builtin_amdgcn_mfma_f32_16x16x32_bf16(a, b2, acc[2], 0, 0, 0);
            }
            // C layout: col = l16 (h-col j), row = quad*4 + r (row within 16-row tile)
            #pragma unroll
            for (int r = 0; r < 4; r++) {
                int rr = rt * 16 + quad * 4 + r;
                if (rr >= S) continue;
                int t = pos_list[off + rr];
                const float* girow = gi + (size_t)t * TH;
                float hp = out[(size_t)(t - 1) * HD + j];
                float rgt = sigm(girow[j] + acc[0][r]);
                float zgt = sigm(girow[1024 + j] + acc[1][r]);
                float ngt = tanh_fast(girow[2048 + j] + rgt * (acc[2][r] + bhn[j]));
                float hv = (1.f - zgt) * ngt + zgt * hp;
                out[(size_t)t * HD + j] = hv;
                out[(size_t)(T_LEN + t) * HD + j] = hv;
                hbw[(size_t)t * HD + j] = f2bf(hv);
            }
        }
        return;
    }

    // ---------------- LDS path (verified round-0 form) ----------------
    int r0 = blockIdx.y * 64;
    if (r0 >= S) return;
    int j0 = blockIdx.x * 64;
    __shared__ unsigned short As[4 * 64 * 32];    // 16 KB (four 32-K sub-tiles)
    __shared__ unsigned short Bs[4 * 192 * 32];   // 48 KB (row: gate g*64 + jj)
    int wm = wave & 1, wn = wave >> 1;

    // A gather: 256 chunks per sub-tile; chunk id = tid; row=tid>>2, sub=tid&3.
    int arow = tid >> 2, sub = tid & 3;
    bool av = (r0 + arow) < S;
    int t_a = av ? pos_list[off + r0 + arow] : 1;
    const unsigned short* hsrc = hb + (size_t)(t_a - 1) * HD + sub * 8;

    f32x4 acc[2][6] = {};
    for (int kb = 0; kb < 8; kb++) {
        int k0 = kb * 128;
        for (int ks = 0; ks < 4; ks++) {
            int kk0 = k0 + ks * 32;
            for (int p = 0; p < 3; p++) {      // B sub-tile: 768 chunks
                int c = tid + p * 256;
                int row = c >> 2, q = c & 3;
                int g = row >> 6, jj = row & 63;
                gld16(WhT + (size_t)(g * 1024 + j0 + jj) * 1024 + kk0 + q * 8,
                      Bs + ks * 6144 + c * 8);
            }
            // A sub-tile: 256 chunks (gathered rows; garbage rows >= S harmless)
            gld16(hsrc + kk0, As + ks * 2048 + tid * 8);
        }
        __syncthreads();
        for (int ks = 0; ks < 4; ks++) {
            bf16x8 af[2];
            for (int i = 0; i < 2; i++)
                af[i] = *(const bf16x8*)(As + ks * 2048 + (wm * 32 + i * 16 + l16) * 32 + quad * 8);
            for (int n = 0; n < 6; n++) {
                int g = n >> 1, jh = n & 1;
                bf16x8 bv = *(const bf16x8*)(Bs + ks * 6144 + (g * 64 + wn * 32 + jh * 16 + l16) * 32 + quad * 8);
                for (int i = 0; i < 2; i++)
                    acc[i][n] = __builtin_amdgcn_mfma_f32_16x16x32_bf16(af[i], bv, acc[i][n], 0, 0, 0);
            }
        }
        __syncthreads();
    }
    // epilogue: rows r0 + wm*32 + i*16 + quad*4 + r ; cols j0 + wn*32 + jh*16 + l16
    for (int i = 0; i < 2; i++) {
        for (int r = 0; r < 4; r++) {
            int rr = r0 + wm * 32 + i * 16 + quad * 4 + r;
            if (rr >= S) continue;
            int t = pos_list[off + rr];
            const float* girow = gi + (size_t)t * TH;
            const float* hprow = out + (size_t)(t - 1) * HD;
            float* o1 = out + (size_t)t * HD;
            float* o2 = out + (size_t)(T_LEN + t) * HD;
            unsigned short* hbrow = hbw + (size_t)t * HD;
            for (int jh = 0; jh < 2; jh++) {
                int j = j0 + wn * 32 + jh * 16 + l16;
                float ghr = acc[i][0 + jh][r];
                float ghz = acc[i][2 + jh][r];
                float ghn = acc[i][4 + jh][r];
                float rg = sigm(girow[j] + ghr);
                float zg = sigm(girow[1024 + j] + ghz);
                float ng = tanh_fast(girow[2048 + j] + rg * (ghn + bhn[j]));
                float h = (1.f - zg) * ng + zg * hprow[j];
                o1[j] = h;
                o2[j] = h;
                hbrow[j] = f2bf(h);
            }
        }
    }
}

// ---------------- tail: positions with local_step >= NB-1, sequential per time order ----
// Parallel (16 blocks x 64 h-cols) WITHOUT cooperative launch: r7 suggests coop launch
// carries fixed wall overhead. Inter-block barrier is manual: each thread
// __threadfence (release), block arrives via atomicAdd on a counter zeroed by
// meta_kernel, block 0 threads spin on device-scope atomic reads, then acquire fence.
// 16 blocks on 256 CUs launched alone in-stream are co-resident. If S==0, exits early
// before any barrier.
__global__ __launch_bounds__(256) void tail_pll(const float* __restrict__ gi,
                                                const float* __restrict__ bhn,
                                                const unsigned short* __restrict__ WhT,
                                                const int* __restrict__ pos_list,
                                                const int* __restrict__ meta,
                                                int* __restrict__ sync,
                                                float* __restrict__ out) {
    int S = meta[NB - 1];
    if (S == 0) return;
    __shared__ int pos[T_LEN];        // 32 KB: correctness path for any S
    __shared__ float hsh[HD];
    __shared__ float dots[192];
    int off = meta[NB + NB - 1];
    int tid = threadIdx.x;
    int j0 = blockIdx.x * 64;
    for (int i = tid; i < S; i += 256) pos[i] = pos_list[off + i];
    __syncthreads();
    if (tid == 0) {   // insertion sort by t (S expected tiny; redundant per block)
        for (int i = 1; i < S; i++) {
            int v = pos[i], j = i - 1;
            while (j >= 0 && pos[j] > v) { pos[j + 1] = pos[j]; j--; }
            pos[j + 1] = v;
        }
    }
    __syncthreads();
    for (int s = 0; s < S; s++) {
        int t = pos[s];
        for (int u = 0; u < 4; u++)    // stage h_prev (f32, from out)
            hsh[tid + u * 256] = out[(size_t)(t - 1) * HD + tid + u * 256];
        __syncthreads();
        if (tid < 192) {
            int g = tid >> 6, jj = tid & 63;
            int col = g * 1024 + j0 + jj;
            const unsigned short* wrow = WhT + (size_t)col * 1024;
            float acc = 0.f;
            for (int kk = 0; kk < 1024; kk += 8) {
                bf16x8 wv = *(const bf16x8*)(wrow + kk);
                f32x4 h0 = *(const f32x4*)(hsh + kk);
                f32x4 h1 = *(const f32x4*)(hsh + kk + 4);
                acc += h0[0] * bf2f((unsigned short)wv[0]) + h0[1] * bf2f((unsigned short)wv[1])
                     + h0[2] * bf2f((unsigned short)wv[2]) + h0[3] * bf2f((unsigned short)wv[3])
                     + h1[0] * bf2f((unsigned short)wv[4]) + h1[1] * bf2f((unsigned short)wv[5])
                     + h1[2] * bf2f((unsigned short)wv[6]) + h1[3] * bf2f((unsigned short)wv[7]);
            }
            dots[tid] = acc;
        }
        __syncthreads();
        if (tid < 64) {
            int j = j0 + tid;
            float rg = sigm(gi[(size_t)t * TH + j] + dots[tid]);
            float zg = sigm(gi[(size_t)t * TH + 1024 + j] + dots[64 + tid]);
            float ng = tanh_fast(gi[(size_t)t * TH + 2048 + j] + rg * (dots[128 + tid] + bhn[j]));
            float hv = (1.f - zg) * ng + zg * hsh[j];
            out[(size_t)t * HD + j] = hv;
            out[(size_t)(T_LEN + t) * HD + j] = hv;
        }
        // ---- manual device-scope inter-block barrier ----
        __threadfence();               // release: flush this thread's stores
        __syncthreads();               // all threads in block fenced
        if (tid == 0) {
            atomicAdd(sync, 1);        // arrive
            int tgt = 16 * (s + 1);
            while (atomicAdd(sync, 0) < tgt)   // device-scope read; spin
                __builtin_amdgcn_s_sleep(8);
        }
        __syncthreads();
        __threadfence();               // acquire: next step reads fresh out[]
    }
}

extern "C" void kernel_launch(void* const* d_in, const int* in_sizes, int n_in,
                              void* d_out, int out_size, void* d_ws, size_t ws_size,
                              hipStream_t stream) {
    const float* X          = (const float*)d_in[0];
    const int*   term       = (const int*)d_in[1];
    const float* last_state = (const float*)d_in[2];
    const float* Wi         = (const float*)d_in[3];
    const float* bi         = (const float*)d_in[4];
    const float* Wh         = (const float*)d_in[5];
    const float* bhn        = (const float*)d_in[6];
    float* out = (float*)d_out;

    char* ws = (char*)d_ws;
    float*          gi       = (float*)ws;                         // 100,663,296 B
    unsigned short* Xb       = (unsigned short*)(ws + 100663296);  // 16,777,216 B (reused as hb)
    unsigned short* hb       = Xb;  // Xb dead after gemm_gi; stream order guarantees safety
    unsigned short* WiT      = (unsigned short*)(ws + 117440512);  //  6,291,456 B
    unsigned short* WhT      = (unsigned short*)(ws + 123731968);  //  6,291,456 B
    int*            pos_list = (int*)(ws + 130023424);             //     32,768 B
    int*            meta     = (int*)(ws + 130056192);             //        512 B
    int*            syncv    = meta + 48;                          // tail barrier counter

    cast_x<<<dim3(8192), dim3(256), 0, stream>>>(X, Xb);
    transpose_cast<<<dim3(48, 16, 2), dim3(256), 0, stream>>>(Wi, Wh, WiT, WhT);
    meta_kernel<<<dim3(1), dim3(1024), 0, stream>>>(term, last_state, pos_list, meta);
    gemm_gi<<<dim3(24, 64), dim3(256), 0, stream>>>(Xb, WiT, bi, gi);
    pass0_kernel<<<dim3(8192), dim3(256), 0, stream>>>(gi, bhn, last_state, Wh, term, pos_list, meta, out, hb);
    for (int k = 1; k < NB - 1; k++) {
        int rows_max = T_LEN / (k + 1);     // S_k <= T/(k+1)
        int gy = (rows_max + 63) / 64;
        pass_gemm<<<dim3(16, gy), dim3(256), 0, stream>>>(gi, bhn, WhT, hb, out, hb, pos_list, meta, k);
    }
    tail_pll<<<dim3(16), dim3(256), 0, stream>>>(gi, bhn, WhT, pos_list, meta, syncv, out);
}